// Round 13
// baseline (609.320 us; speedup 1.0000x reference)
//
#include <hip/hip_runtime.h>
#include <hip/hip_bf16.h>

#define HDIM 128
#define NREL 16
#define NBASES 8
#define KSLOTS 17            // 16 relations + self-loop
#define KDIM (KSLOTS * HDIM) // 2176
#define LDSA 136             // bf16 LDS row stride (128+8): 2-way alias, free (m136)
#define TILE 64              // output rows per block
#define BINS (TILE * NREL)   // 1024 bins per block

typedef short bf16x8 __attribute__((ext_vector_type(8)));
typedef short s16x4 __attribute__((ext_vector_type(4)));
typedef float f32x4 __attribute__((ext_vector_type(4)));

static __device__ __forceinline__ short f2bf(float x) {
    __hip_bfloat16 b = __float2bfloat16(x);
    return *(short*)&b;
}
static __device__ __forceinline__ float bf2f(short u) {
    unsigned v = ((unsigned)(unsigned short)u) << 16;
    return __uint_as_float(v);
}

// ---------------- weight prep ----------------
// wtL[o][r*128+i] = W_r[i][o] = sum_b wcomp[r][b]*basis[b][i][o]   (bf16)
__global__ void compute_wt(const float* __restrict__ basis,
                           const float* __restrict__ wcomp,
                           short* __restrict__ wtL) {
    int ro = blockIdx.x;
    int r = ro >> 7, o = ro & 127;
    int i = threadIdx.x;
    float acc = 0.f;
#pragma unroll
    for (int b = 0; b < NBASES; ++b)
        acc += wcomp[r * NBASES + b] * basis[(b * HDIM + i) * HDIM + o];
    wtL[(size_t)o * KDIM + r * HDIM + i] = f2bf(acc);
}

// wtL[o][2048+i] = loop_w[i][o]
__global__ void transposeL(const float* __restrict__ in, short* __restrict__ wtL) {
    int o = blockIdx.x, i = threadIdx.x;
    wtL[(size_t)o * KDIM + NREL * HDIM + i] = f2bf(in[i * HDIM + o]);
}

// fp32 -> bf16 cast (vectorized)
__global__ void cast_bf16(const float* __restrict__ in, short* __restrict__ out, int n4) {
    for (int i = blockIdx.x * blockDim.x + threadIdx.x; i < n4; i += gridDim.x * blockDim.x) {
        f32x4 v = ((const f32x4*)in)[i];
        s16x4 o;
#pragma unroll
        for (int j = 0; j < 4; ++j) o[j] = f2bf(v[j]);
        ((s16x4*)out)[i] = o;
    }
}

__global__ void zero_i32(int* __restrict__ p, int n) {
    int i = blockIdx.x * blockDim.x + threadIdx.x;
    if (i < n) p[i] = 0;
}

// ---------------- counting sort by key = dst*16 + rel (800K bins) ----------------
__global__ __launch_bounds__(256) void hist_k(const int* __restrict__ dst,
                                              const int* __restrict__ rel, int n,
                                              int* __restrict__ hist) {
    for (int i = blockIdx.x * blockDim.x + threadIdx.x; i < n; i += gridDim.x * blockDim.x)
        atomicAdd(&hist[dst[i] * NREL + rel[i]], 1);
}

__global__ __launch_bounds__(1024) void scan_p1(const int* __restrict__ hist, int n,
                                                int* __restrict__ off, int* __restrict__ part) {
    __shared__ int sh[1024];
    int t = threadIdx.x, b = blockIdx.x;
    int i = b * 1024 + t;
    int x = (i < n) ? hist[i] : 0;
    sh[t] = x;
    __syncthreads();
    for (int d = 1; d < 1024; d <<= 1) {
        int v = sh[t];
        int u = (t >= d) ? sh[t - d] : 0;
        __syncthreads();
        sh[t] = v + u;
        __syncthreads();
    }
    if (i < n) off[i] = sh[t] - x;
    if (t == 1023) part[b] = sh[t];
}

__global__ __launch_bounds__(1024) void scan_p2(int* __restrict__ part, int nb) {
    __shared__ int sh[1024];
    int t = threadIdx.x;
    int x = (t < nb) ? part[t] : 0;
    sh[t] = x;
    __syncthreads();
    for (int d = 1; d < 1024; d <<= 1) {
        int v = sh[t];
        int u = (t >= d) ? sh[t - d] : 0;
        __syncthreads();
        sh[t] = v + u;
        __syncthreads();
    }
    if (t < nb) part[t] = sh[t] - x;
}

__global__ __launch_bounds__(1024) void scan_p3(int* __restrict__ off, const int* __restrict__ part,
                                                int n, int nk, int* __restrict__ cur) {
    int i = blockIdx.x * 1024 + threadIdx.x;
    if (i < n) {
        int v = off[i] + part[blockIdx.x];
        off[i] = v;
        if (i < nk) cur[i] = v;
    }
}

// place edges: edge2[p] = src
__global__ __launch_bounds__(256) void scatter_k(const int* __restrict__ src,
                                                 const int* __restrict__ dst,
                                                 const int* __restrict__ rel, int n,
                                                 int* __restrict__ cur,
                                                 int* __restrict__ edge2) {
    for (int i = blockIdx.x * blockDim.x + threadIdx.x; i < n; i += gridDim.x * blockDim.x) {
        int k = dst[i] * NREL + rel[i];
        int p = atomicAdd(&cur[k], 1);
        edge2[p] = src[i];
    }
}

// ---------------- fused layer: out = relu([agg_r|h] @ WstackT + bias) ----------------
// Block = 64 rows x 128 cols, 256 threads (4 waves, wave-tile 32x64) — R11's
// proven MFMA core with the A-source built IN-KERNEL (no AGG materialization,
// no HBM round-trip). 3-stage pipeline, no dependent-load chain in any slot:
//   slot k: [issue h-gathers(k+1), srcs known since k-1] [issue edge-idx
//   loads(k+2)] [issue B(k+1) reg-loads] [MFMA(k) -- pure LDS] [barrier]
//   [sum gathers -> ds_write A(k+1); write B(k+1)] [barrier]
// Each thread stages the FULL 32-short quarter of its row (4 x bf16x8 per
// edge — R12's bug was staging only half). deg>2 tail (P~8%) re-gathers
// per-vector in consume (8-float live accumulator keeps VGPR ~140 < the
// 3-wave/SIMD cap). LDS 54.3KB -> 3 blocks/CU.
__global__ __launch_bounds__(256, 3) void rgcn_fused(
    const short* __restrict__ h,      // bf16 [N][128]
    const short* __restrict__ wtL,    // [128 o][2176 k] bf16
    const int* __restrict__ off,      // [NK+1] bin offsets (key = dst*16+rel)
    const int* __restrict__ edge2,    // src per edge, key-sorted
    const float* __restrict__ bias,   // [128]
    short* __restrict__ out_bf,       // layer-1 output (bf16) or nullptr
    float* __restrict__ out_f,        // layer-2 output (fp32) or nullptr
    int n, int NK) {
    __shared__ short As[TILE * LDSA];        // 17408 B
    __shared__ short Bs[128 * LDSA];         // 34816 B
    __shared__ unsigned short sOff[BINS + 1];// 2050 B (u16 deltas from base)

    int tid = threadIdx.x;
    int row0 = blockIdx.x * TILE;
    int wave = tid >> 6, lane = tid & 63;
    int mq = (wave & 1) * 32, nq = (wave >> 1) * 64;
    int lr = lane & 15, quad = lane >> 4;
    int r2 = tid >> 2, ca = (tid & 3) * 32;   // A staging: row, 32-short quarter
    int rb = tid >> 1, hb = (tid & 1) * 64;   // B staging: row, 64-short half

    // ---- prologue: bin offsets -> LDS as u16 deltas (block range ~1024 edges) ----
    int base = off[row0 * NREL];
    for (int i = tid; i <= BINS; i += 256) {
        int gi = row0 * NREL + i;
        if (gi > NK) gi = NK;
        sOff[i] = (unsigned short)(off[gi] - base);
    }
    __syncthreads();

    // ---- pipeline state ----
    int dgA = 0, ebA = 0, sA0 = 0, sA1 = 0;   // slot whose gathers are in flight
    int dgB = 0, ebB = 0, sB0 = 0, sB1 = 0;   // slot whose edge-srcs are loading
    bf16x8 va0[4], va1[4];   // gathered rows: FULL 32-short quarter per edge
    bf16x8 bpf[8];           // B slot staging

    auto loadE = [&](int ks) {   // load edge srcs for slot ks -> B-state
        if (ks == 16) {          // self-loop
            int gr = row0 + r2;
            dgB = (gr < n) ? 1 : 0;
            ebB = 0; sB0 = gr; sB1 = 0;
        } else {
            int i0 = r2 * NREL + ks;
            int a = base + sOff[i0];
            int b = base + sOff[i0 + 1];
            dgB = b - a; ebB = a;
            sB0 = (dgB > 0) ? edge2[a] : 0;
            sB1 = (dgB > 1) ? edge2[a + 1] : 0;
        }
    };
    auto rotate = [&]() { dgA = dgB; ebA = ebB; sA0 = sB0; sA1 = sB1; };
    auto issueH = [&]() {        // gather full quarters of up to 2 edges
        if (dgA > 0) {
            const short* sp = h + (size_t)sA0 * HDIM + ca;
#pragma unroll
            for (int v = 0; v < 4; ++v) va0[v] = *(const bf16x8*)(sp + v * 8);
        }
        if (dgA > 1) {
            const short* sp = h + (size_t)sA1 * HDIM + ca;
#pragma unroll
            for (int v = 0; v < 4; ++v) va1[v] = *(const bf16x8*)(sp + v * 8);
        }
    };
    auto consumeA = [&]() {      // sum gathers -> As (A-state slot)
        short* dp = As + r2 * LDSA + ca;
        if (dgA <= 0) {
#pragma unroll
            for (int v = 0; v < 4; ++v) *(bf16x8*)(dp + v * 8) = (bf16x8)0;
        } else if (dgA == 1) {
#pragma unroll
            for (int v = 0; v < 4; ++v) *(bf16x8*)(dp + v * 8) = va0[v];
        } else {
#pragma unroll
            for (int v = 0; v < 4; ++v) {
                float ac[8];
#pragma unroll
                for (int c = 0; c < 8; ++c) ac[c] = bf2f(va0[v][c]) + bf2f(va1[v][c]);
                for (int j = 2; j < dgA; ++j) {      // rare tail (P~8%)
                    int s = edge2[ebA + j];
                    bf16x8 w = *(const bf16x8*)(h + (size_t)s * HDIM + ca + v * 8);
#pragma unroll
                    for (int c = 0; c < 8; ++c) ac[c] += bf2f(w[c]);
                }
                bf16x8 o;
#pragma unroll
                for (int c = 0; c < 8; ++c) o[c] = f2bf(ac[c]);
                *(bf16x8*)(dp + v * 8) = o;
            }
        }
    };
    auto loadB = [&](int ks) {
        const short* bp = wtL + (size_t)rb * KDIM + ks * HDIM + hb;
#pragma unroll
        for (int j = 0; j < 8; ++j) bpf[j] = *(const bf16x8*)(bp + j * 8);
    };
    auto writeB = [&]() {
        short* bd = Bs + rb * LDSA + hb;
#pragma unroll
        for (int j = 0; j < 8; ++j) *(bf16x8*)(bd + j * 8) = bpf[j];
    };

    // ---- pipeline prologue: fill slot 0 ----
    loadE(0); rotate();          // A-state = slot 0
    issueH();                    // gathers for slot 0 in flight
    loadE(1);                    // B-state = slot 1
    loadB(0);
    consumeA();                  // waits slot-0 gathers (once), As = slot 0
    writeB();                    // Bs = slot 0
    rotate();                    // A-state = slot 1
    __syncthreads();

    f32x4 acc[2][4] = {};

#pragma unroll 1
    for (int ks = 0; ks < KSLOTS; ++ks) {
        if (ks + 1 < KSLOTS) issueH();        // gathers(ks+1): addrs ready, no wait
        if (ks + 2 < KSLOTS) loadE(ks + 2);   // edge idx (ks+2), independent
        if (ks + 1 < KSLOTS) loadB(ks + 1);   // B(ks+1), L2-hot

        // MFMA slot ks — reads only LDS; no global dependency
#pragma unroll
        for (int kk = 0; kk < 4; ++kk) {
            int kb = kk * 32 + quad * 8;
            bf16x8 a2[2], b4[4];
#pragma unroll
            for (int mi = 0; mi < 2; ++mi)
                a2[mi] = *(const bf16x8*)(As + (mq + mi * 16 + lr) * LDSA + kb);
#pragma unroll
            for (int ni = 0; ni < 4; ++ni)
                b4[ni] = *(const bf16x8*)(Bs + (nq + ni * 16 + lr) * LDSA + kb);
#pragma unroll
            for (int mi = 0; mi < 2; ++mi)
#pragma unroll
                for (int ni = 0; ni < 4; ++ni)
                    acc[mi][ni] = __builtin_amdgcn_mfma_f32_16x16x32_bf16(a2[mi], b4[ni], acc[mi][ni], 0, 0, 0);
        }
        __syncthreads();                      // LDS reads done (loads have landed)
        if (ks + 1 < KSLOTS) {
            consumeA();                       // As <- slot ks+1 aggregates
            writeB();                         // Bs <- slot ks+1
            rotate();                         // A-state = slot ks+2
            __syncthreads();
        }
    }

    // epilogue: bias + relu, single store.  C/D: col=lane&15, row=quad*4+reg [m89]
#pragma unroll
    for (int mi = 0; mi < 2; ++mi) {
#pragma unroll
        for (int reg = 0; reg < 4; ++reg) {
            int g = row0 + mq + mi * 16 + quad * 4 + reg;
            if (g < n) {
                size_t gd = (size_t)g * HDIM;
#pragma unroll
                for (int ni = 0; ni < 4; ++ni) {
                    int nn = nq + ni * 16 + lr;
                    float v = acc[mi][ni][reg] + bias[nn];
                    v = v > 0.f ? v : 0.f;
                    if (out_bf) out_bf[gd + nn] = f2bf(v);
                    else        out_f[gd + nn] = v;
                }
            }
        }
    }
}

extern "C" void kernel_launch(void* const* d_in, const int* in_sizes, int n_in,
                              void* d_out, int out_size, void* d_ws, size_t ws_size,
                              hipStream_t stream) {
    const float* emb    = (const float*)d_in[0];
    const float* basis1 = (const float*)d_in[1];
    const float* wc1    = (const float*)d_in[2];
    const float* lw1    = (const float*)d_in[3];
    const float* bias1  = (const float*)d_in[4];
    const float* basis2 = (const float*)d_in[5];
    const float* wc2    = (const float*)d_in[6];
    const float* lw2    = (const float*)d_in[7];
    const float* bias2  = (const float*)d_in[8];
    const int* src = (const int*)d_in[9];
    const int* dst = (const int*)d_in[10];
    const int* rel = (const int*)d_in[11];

    int n_ent = in_sizes[0] / HDIM;
    int n_edges = in_sizes[9];
    int NK = n_ent * NREL;
    int NK1 = NK + 1;

    char* ws = (char*)d_ws;
    size_t wo = 0;
    auto alloc = [&](size_t bytes) {
        void* p = ws + wo;
        wo = (wo + bytes + 255) & ~(size_t)255;
        return p;
    };
    int* hist   = (int*)alloc((size_t)NK1 * 4);
    int* off    = (int*)alloc((size_t)NK1 * 4);
    int* cur    = (int*)alloc((size_t)NK * 4);
    int* part   = (int*)alloc(4096);
    int* edge2  = (int*)alloc((size_t)n_edges * 4);
    short* wtL1 = (short*)alloc((size_t)HDIM * KDIM * 2);
    short* wtL2 = (short*)alloc((size_t)HDIM * KDIM * 2);
    short* h0   = (short*)alloc((size_t)n_ent * HDIM * 2);
    short* h1   = (short*)alloc((size_t)n_ent * HDIM * 2);

    // weight prep + input cast
    compute_wt<<<NREL * HDIM, HDIM, 0, stream>>>(basis1, wc1, wtL1);
    compute_wt<<<NREL * HDIM, HDIM, 0, stream>>>(basis2, wc2, wtL2);
    transposeL<<<HDIM, HDIM, 0, stream>>>(lw1, wtL1);
    transposeL<<<HDIM, HDIM, 0, stream>>>(lw2, wtL2);
    cast_bf16<<<512, 256, 0, stream>>>(emb, h0, n_ent * HDIM / 4);

    // counting sort by key = dst*16+rel (once; reused by both layers)
    zero_i32<<<(NK1 + 255) / 256, 256, 0, stream>>>(hist, NK1);
    hist_k<<<1024, 256, 0, stream>>>(dst, rel, n_edges, hist);
    int nsb = (NK1 + 1023) / 1024;
    scan_p1<<<nsb, 1024, 0, stream>>>(hist, NK1, off, part);
    scan_p2<<<1, 1024, 0, stream>>>(part, nsb);
    scan_p3<<<nsb, 1024, 0, stream>>>(off, part, NK1, NK, cur);
    scatter_k<<<1024, 256, 0, stream>>>(src, dst, rel, n_edges, cur, edge2);

    int gtiles = (n_ent + TILE - 1) / TILE;

    // fused layers: no AGG materialization, no atomics, single store per output
    rgcn_fused<<<gtiles, 256, 0, stream>>>(h0, wtL1, off, edge2, bias1,
                                           h1, nullptr, n_ent, NK);
    rgcn_fused<<<gtiles, 256, 0, stream>>>(h1, wtL2, off, edge2, bias2,
                                           nullptr, (float*)d_out, n_ent, NK);
}